// Round 4
// baseline (27210.223 us; speedup 1.0000x reference)
//
#include <hip/hip_runtime.h>
#include <math.h>

#define B 256
#define T 512
#define H 1024
#define CODE 3
#define NBLK 256

typedef _Float16 f16x8 __attribute__((ext_vector_type(8)));
typedef float f32x4 __attribute__((ext_vector_type(4)));

__device__ __forceinline__ float sigmoidf_(float x) { return 1.0f / (1.0f + __expf(-x)); }
__device__ __forceinline__ float tanhf_(float x) {
    float ax = fabsf(x);
    float t = __expf(-2.0f * ax);
    float r = (1.0f - t) / (1.0f + t);
    return x < 0.f ? -r : r;
}

// Sense-reversing grid barrier. Safe: grid = 256 = #CUs, VGPR>128 forces
// <=1 block/CU by regs, so all blocks are always resident. cnt/gen are
// memset to 0 on every kernel_launch (ws is poisoned once, never restored).
__device__ __forceinline__ void grid_barrier(unsigned* cnt, unsigned* gen, int tid) {
    __syncthreads();
    if (tid == 0) {
        __threadfence();  // release: drain stores, wb L2 (cross-XCD visibility)
        unsigned g = __hip_atomic_load(gen, __ATOMIC_RELAXED, __HIP_MEMORY_SCOPE_AGENT);
        unsigned old = __hip_atomic_fetch_add(cnt, 1u, __ATOMIC_ACQ_REL, __HIP_MEMORY_SCOPE_AGENT);
        if (old == NBLK - 1u) {
            __hip_atomic_store(cnt, 0u, __ATOMIC_RELAXED, __HIP_MEMORY_SCOPE_AGENT);
            __hip_atomic_fetch_add(gen, 1u, __ATOMIC_RELEASE, __HIP_MEMORY_SCOPE_AGENT);
        } else {
            while (__hip_atomic_load(gen, __ATOMIC_RELAXED, __HIP_MEMORY_SCOPE_AGENT) == g)
                __builtin_amdgcn_s_sleep(1);
        }
        __threadfence();  // acquire: invalidate L2 so other XCDs' writes are seen
    }
    __syncthreads();
}

// Load this wave's 48 B-fragments (3 gates x 16 k-chunks of its K-half) from
// f32 weights, converting to f16. j = this lane's B row; one-time cost.
__device__ __forceinline__ void load_weights(f16x8 (&wB)[48], const float* __restrict__ W,
                                             int j, int kh, int kg) {
#pragma unroll
    for (int g = 0; g < 3; ++g)
#pragma unroll
        for (int i = 0; i < 16; ++i) {
            const float* p = W + (((size_t)g << 10) + j) * 1024 + (kh << 9) + (i << 5) + (kg << 3);
            float4 u = *(const float4*)p;
            float4 v = *(const float4*)(p + 4);
            f16x8 o;
            o[0] = (_Float16)u.x; o[1] = (_Float16)u.y; o[2] = (_Float16)u.z; o[3] = (_Float16)u.w;
            o[4] = (_Float16)v.x; o[5] = (_Float16)v.y; o[6] = (_Float16)v.z; o[7] = (_Float16)v.w;
            wB[g * 16 + i] = o;
        }
}

// One GRU phase: 512 steps. Weights in wB (registers), h f32 master in hreg.
// h16 ping-pong: step t reads buf[t&1], writes buf[(t+1)&1].
template <bool DEC>
__device__ __forceinline__ void phase(
    int b0, int j0, int jt, int j, int np, int kh, int kg, int r16, int tid, int lane,
    const f16x8 (&wB)[48], float (&hreg)[4],
    _Float16* __restrict__ h16A, _Float16* __restrict__ h16B,
    const float* __restrict__ Wih, const float* __restrict__ bih,
    const float* __restrict__ bhh,
    const float* __restrict__ input, const float* __restrict__ Wout, float bout_v,
    float* __restrict__ xpart, float* __restrict__ outp,
    unsigned* bcnt, unsigned* bgen,
    char* Als, f32x4 (*red)[3][64], float* xv_s, float (*xnp)[16])
{
    const float wi_r = Wih[j], wi_z = Wih[1024 + j], wi_n = Wih[2048 + j];
    const float bi_r = bih[j], bi_z = bih[1024 + j], bi_n = bih[2048 + j];
    const float bh_r = bhh[j], bh_z = bhh[1024 + j], bh_n = bhh[2048 + j];
    const float wo = DEC ? Wout[j] : 0.f;

    for (int t = 0; t < T; ++t) {
        const _Float16* hp = (t & 1) ? h16B : h16A;
        _Float16* hn = (t & 1) ? h16A : h16B;

        // decoder: gather x_t = sum of 16 j-group partials (+bout); write out[:,t-1]
        if (DEC) {
            if (tid < 16) {
                float s = 0.f;
                if (t > 0) {
                    const float* xp = xpart + ((t - 1) & 1) * 4096 + (size_t)(b0 + tid) * 16;
#pragma unroll
                    for (int q = 0; q < 16; ++q) s += xp[q];
                    s += bout_v;
                    if (jt == 0) outp[(size_t)(b0 + tid) * T + (t - 1)] = s;
                }
                xv_s[tid] = s;
            }
        }

        // stage A-tile [16 x 1024] f16 into LDS, XOR-swizzled (k_byte ^= (row&7)<<4)
#pragma unroll
        for (int i = 0; i < 4; ++i) {
            int c = i * 512 + tid;
            int row = c >> 7, kc = c & 127;
            f16x8 v = *(const f16x8*)(hp + ((size_t)(b0 + row) << 10) + (kc << 3));
            *(f16x8*)(Als + row * 2048 + ((kc * 16) ^ ((row & 7) << 4))) = v;
        }
        __syncthreads();

        f32x4 aR = {0.f, 0.f, 0.f, 0.f}, aZ = {0.f, 0.f, 0.f, 0.f}, aN = {0.f, 0.f, 0.f, 0.f};
#pragma unroll
        for (int i = 0; i < 16; ++i) {
            int kb = (kh << 10) + (i << 6) + (kg << 4);
            f16x8 a = *(const f16x8*)(Als + (r16 << 11) + (kb ^ ((r16 & 7) << 4)));
            aR = __builtin_amdgcn_mfma_f32_16x16x32_f16(a, wB[i], aR, 0, 0, 0);
            aZ = __builtin_amdgcn_mfma_f32_16x16x32_f16(a, wB[16 + i], aZ, 0, 0, 0);
            aN = __builtin_amdgcn_mfma_f32_16x16x32_f16(a, wB[32 + i], aN, 0, 0, 0);
        }

        if (kh == 1) {
            red[np][0][lane] = aR; red[np][1][lane] = aZ; red[np][2][lane] = aN;
        }
        __syncthreads();

        if (kh == 0) {
            f32x4 rR = red[np][0][lane], rZ = red[np][1][lane], rN = red[np][2][lane];
            float xw[4];
#pragma unroll
            for (int reg = 0; reg < 4; ++reg) {
                int brow = kg * 4 + reg;
                int b = b0 + brow;
                float xv = DEC ? xv_s[brow] : input[(size_t)b * T + t];
                float r = sigmoidf_(xv * wi_r + bi_r + aR[reg] + rR[reg] + bh_r);
                float z = sigmoidf_(xv * wi_z + bi_z + aZ[reg] + rZ[reg] + bh_z);
                float n = tanhf_(xv * wi_n + bi_n + r * (aN[reg] + rN[reg] + bh_n));
                float hNew = (1.f - z) * n + z * hreg[reg];
                hreg[reg] = hNew;
                hn[((size_t)b << 10) + j] = (_Float16)hNew;
                xw[reg] = hNew * wo;
            }
            if (DEC) {
#pragma unroll
                for (int reg = 0; reg < 4; ++reg) {
                    float v = xw[reg];
                    v += __shfl_xor(v, 1); v += __shfl_xor(v, 2);
                    v += __shfl_xor(v, 4); v += __shfl_xor(v, 8);
                    if (r16 == 0) xnp[np][kg * 4 + reg] = v;
                }
            }
        }
        if (DEC) {
            __syncthreads();
            if (tid < 16) {
                float s = xnp[0][tid] + xnp[1][tid] + xnp[2][tid] + xnp[3][tid];
                xpart[(t & 1) * 4096 + (size_t)(b0 + tid) * 16 + jt] = s;
            }
        }
        grid_barrier(bcnt, bgen, tid);
    }
}

__global__ __launch_bounds__(512, 2) void gru_persistent(
    const float* __restrict__ input, const float* __restrict__ h_init,
    const float* __restrict__ Wih_e, const float* __restrict__ Whh_e,
    const float* __restrict__ bih_e, const float* __restrict__ bhh_e,
    const float* __restrict__ Wenc, const float* __restrict__ benc,
    const float* __restrict__ Wdec, const float* __restrict__ bdec,
    const float* __restrict__ Wih_d, const float* __restrict__ Whh_d,
    const float* __restrict__ bih_d, const float* __restrict__ bhh_d,
    const float* __restrict__ Wout, const float* __restrict__ boutp,
    float* __restrict__ featOut, float* __restrict__ outp,
    _Float16* __restrict__ h16A, _Float16* __restrict__ h16B,
    float* __restrict__ xpart, float* __restrict__ fpart,
    unsigned* bcnt, unsigned* bgen)
{
    __shared__ __align__(16) char Als[32768];
    __shared__ f32x4 red[4][3][64];
    __shared__ float xv_s[16];
    __shared__ float xnp[4][16];
    __shared__ float fp_np[4][16][3];
    __shared__ float feats[16][3];

    const int tid = threadIdx.x;
    const int lane = tid & 63;
    const int w = tid >> 6;      // 0..7
    const int kh = w & 1;        // K-half
    const int np = w >> 1;       // 0..3 n-quadrant
    const int kg = lane >> 4;    // 0..3
    const int r16 = lane & 15;
    const int bid = blockIdx.x;
    const int jt = bid & 15, bt = bid >> 4;
    const int b0 = bt * 16, j0 = jt * 64;
    const int j = j0 + np * 16 + r16;
    const float bout_v = boutp[0];

    f16x8 wB[48];
    float hreg[4] = {0.f, 0.f, 0.f, 0.f};

    // ---- init: hreg + h16A from h_init ----
    if (kh == 0) {
#pragma unroll
        for (int reg = 0; reg < 4; ++reg) {
            int b = b0 + kg * 4 + reg;
            float v = h_init[((size_t)b << 10) + j];
            hreg[reg] = v;
            h16A[((size_t)b << 10) + j] = (_Float16)v;
        }
    }
    load_weights(wB, Whh_e, j, kh, kg);
    grid_barrier(bcnt, bgen, tid);

    // ---- encoder: 512 steps ----
    phase<false>(b0, j0, jt, j, np, kh, kg, r16, tid, lane, wB, hreg, h16A, h16B,
                 Wih_e, bih_e, bhh_e, input, Wout, bout_v, xpart, outp,
                 bcnt, bgen, Als, red, xv_s, xnp);

    // ---- bottleneck: fpart partials from hreg (hT) ----
    {
        float we0 = Wenc[j], we1 = Wenc[1024 + j], we2 = Wenc[2048 + j];
        if (kh == 0) {
#pragma unroll
            for (int reg = 0; reg < 4; ++reg) {
                float h = hreg[reg];
                float p0 = h * we0, p1 = h * we1, p2 = h * we2;
#pragma unroll
                for (int m = 1; m < 16; m <<= 1) {
                    p0 += __shfl_xor(p0, m);
                    p1 += __shfl_xor(p1, m);
                    p2 += __shfl_xor(p2, m);
                }
                if (r16 == 0) {
                    fp_np[np][kg * 4 + reg][0] = p0;
                    fp_np[np][kg * 4 + reg][1] = p1;
                    fp_np[np][kg * 4 + reg][2] = p2;
                }
            }
        }
        __syncthreads();
        if (tid < 48) {
            int bi = tid / 3, c = tid % 3;
            float s = fp_np[0][bi][c] + fp_np[1][bi][c] + fp_np[2][bi][c] + fp_np[3][bi][c];
            fpart[(size_t)(b0 + bi) * 48 + jt * 3 + c] = s;
        }
        grid_barrier(bcnt, bgen, tid);

        if (tid < 48) {
            int bi = tid / 3, c = tid % 3;
            float s = 0.f;
            const float* fp = fpart + (size_t)(b0 + bi) * 48 + c;
#pragma unroll
            for (int q = 0; q < 16; ++q) s += fp[q * 3];
            float f = sigmoidf_(s + benc[c]);
            feats[bi][c] = f;
            if (jt == 0) featOut[(b0 + bi) * 3 + c] = f;
        }
        __syncthreads();

        // h0 = feats @ Wdec.T + bdec  -> hreg + h16A (decoder t=0 reads h16A)
        if (kh == 0) {
#pragma unroll
            for (int reg = 0; reg < 4; ++reg) {
                int brow = kg * 4 + reg;
                int b = b0 + brow;
                float v = feats[brow][0] * Wdec[j * 3 + 0] + feats[brow][1] * Wdec[j * 3 + 1] +
                          feats[brow][2] * Wdec[j * 3 + 2] + bdec[j];
                hreg[reg] = v;
                h16A[((size_t)b << 10) + j] = (_Float16)v;
            }
        }
        load_weights(wB, Whh_d, j, kh, kg);
        grid_barrier(bcnt, bgen, tid);
    }

    // ---- decoder: 512 steps ----
    phase<true>(b0, j0, jt, j, np, kh, kg, r16, tid, lane, wB, hreg, h16A, h16B,
                Wih_d, bih_d, bhh_d, input, Wout, bout_v, xpart, outp,
                bcnt, bgen, Als, red, xv_s, xnp);

    // ---- final output column: x from step 511 (xpart slot 1) ----
    if (jt == 0 && tid < 16) {
        const float* xp = xpart + 4096 + (size_t)(b0 + tid) * 16;
        float s = 0.f;
#pragma unroll
        for (int q = 0; q < 16; ++q) s += xp[q];
        outp[(size_t)(b0 + tid) * T + (T - 1)] = s + bout_v;
    }
}

__global__ __launch_bounds__(256) void loss_partial(
    const float* __restrict__ input, const float* __restrict__ outp,
    float* __restrict__ partial)
{
    int idx = blockIdx.x * blockDim.x + threadIdx.x;
    float s = 0.f;
    for (int i = idx; i < B * T; i += gridDim.x * blockDim.x) {
        float d = input[i] - outp[i];
        s += d * d;
    }
#pragma unroll
    for (int off = 32; off; off >>= 1) s += __shfl_down(s, off);
    __shared__ float ws[4];
    if ((threadIdx.x & 63) == 0) ws[threadIdx.x >> 6] = s;
    __syncthreads();
    if (threadIdx.x == 0) partial[blockIdx.x] = ws[0] + ws[1] + ws[2] + ws[3];
}

__global__ __launch_bounds__(256) void loss_final(
    const float* __restrict__ partial, float* __restrict__ loss)
{
    int tid = threadIdx.x;
    float s = partial[tid];
#pragma unroll
    for (int off = 32; off; off >>= 1) s += __shfl_down(s, off);
    __shared__ float ws[4];
    if ((tid & 63) == 0) ws[tid >> 6] = s;
    __syncthreads();
    if (tid == 0) loss[0] = (ws[0] + ws[1] + ws[2] + ws[3]) * (1.0f / (float)(B * T));
}

extern "C" void kernel_launch(void* const* d_in, const int* in_sizes, int n_in,
                              void* d_out, int out_size, void* d_ws, size_t ws_size,
                              hipStream_t stream) {
    const float* input = (const float*)d_in[0];
    const float* h_init = (const float*)d_in[1];
    const float* Wih_e = (const float*)d_in[2];
    const float* Whh_e = (const float*)d_in[3];
    const float* bih_e = (const float*)d_in[4];
    const float* bhh_e = (const float*)d_in[5];
    const float* Wenc  = (const float*)d_in[6];
    const float* benc  = (const float*)d_in[7];
    const float* Wdec  = (const float*)d_in[8];
    const float* bdec  = (const float*)d_in[9];
    const float* Wih_d = (const float*)d_in[10];
    const float* Whh_d = (const float*)d_in[11];
    const float* bih_d = (const float*)d_in[12];
    const float* bhh_d = (const float*)d_in[13];
    const float* Wout  = (const float*)d_in[14];
    const float* bout  = (const float*)d_in[15];
    (void)in_sizes; (void)n_in; (void)out_size; (void)ws_size;

    float* out = (float*)d_out;
    float* lossp = out;                    // [1]
    float* feat = out + 1;                 // [B*CODE]
    float* outp = out + 1 + B * CODE;      // [B*T]

    // ---- workspace layout ----
    char* ws = (char*)d_ws;
    _Float16* h16A = (_Float16*)ws;                  ws += (size_t)B * H * 2;
    _Float16* h16B = (_Float16*)ws;                  ws += (size_t)B * H * 2;
    float* xpart = (float*)ws;                       ws += 2 * 4096 * 4;   // [2][256][16]
    float* fpart = (float*)ws;                       ws += (size_t)B * 48 * 4;
    float* partial = (float*)ws;                     ws += 256 * 4;
    unsigned* bar = (unsigned*)ws;                   ws += 2 * sizeof(unsigned);

    // barrier state must start at 0 every call (ws poisoned once, not restored)
    hipMemsetAsync(bar, 0, 2 * sizeof(unsigned), stream);

    gru_persistent<<<dim3(NBLK), dim3(512), 0, stream>>>(
        input, h_init, Wih_e, Whh_e, bih_e, bhh_e, Wenc, benc, Wdec, bdec,
        Wih_d, Whh_d, bih_d, bhh_d, Wout, bout,
        feat, outp, h16A, h16B, xpart, fpart, bar, bar + 1);

    loss_partial<<<256, 256, 0, stream>>>(input, outp, partial);
    loss_final<<<1, 256, 0, stream>>>(partial, lossp);
}

// Round 5
// 15296.886 us; speedup vs baseline: 1.7788x; 1.7788x over previous
//
#include <hip/hip_runtime.h>
#include <math.h>

#define B 256
#define T 512
#define H 1024
#define CODE 3
#define NBLK 256

typedef _Float16 f16x8 __attribute__((ext_vector_type(8)));
typedef float f32x4 __attribute__((ext_vector_type(4)));

__device__ __forceinline__ float sigmoidf_(float x) { return 1.0f / (1.0f + __expf(-x)); }
__device__ __forceinline__ float tanhf_(float x) {
    float ax = fabsf(x);
    float t = __expf(-2.0f * ax);
    float r = (1.0f - t) / (1.0f + t);
    return x < 0.f ? -r : r;
}

// ---- bt-group barrier (16 blocks sharing batch rows) ----
// Each block release-stores a monotone generation g to its OWN padded flag
// line (no RMW); 16 lanes of wave 0 poll the 16 group flags in parallel.
// flags zeroed by hipMemsetAsync each launch; g strictly increases -> no
// reset race, safe across encoder/bottleneck/decoder reuse.
// Blocks are mapped bt = bid&15, jt = bid>>4 so a bt-group = {bt, bt+16, ...}
// lands on ONE XCD (bid%8 == bt%8 for all members): flag + h16 traffic is
// XCD-local, and the 16 groups drift independently (no global convoy).
__device__ __forceinline__ void bt_barrier(volatile unsigned* flags, int bt, int jt,
                                           unsigned g, int tid) {
    __syncthreads();                 // all waves drained their stores (vmcnt 0)
    if (tid < 64) {                  // wave 0 only
        __threadfence();             // release: wb L2 -> h16/xpart agent-visible
        if (tid == 0)
            __hip_atomic_store((unsigned*)&flags[(bt * 16 + jt) * 32], g,
                               __ATOMIC_RELAXED, __HIP_MEMORY_SCOPE_AGENT);
        if (tid < 16) {
            while (__hip_atomic_load((unsigned*)&flags[(bt * 16 + tid) * 32],
                                     __ATOMIC_RELAXED, __HIP_MEMORY_SCOPE_AGENT) < g)
                __builtin_amdgcn_s_sleep(1);
        }
        __threadfence();             // acquire: inv L2 -> see remote h16
    }
    __syncthreads();
}

// Load this wave's 48 B-fragments (3 gates x 16 k-chunks of its K-half) from
// f32 weights, converting to f16. j = this lane's B row; one-time cost.
__device__ __forceinline__ void load_weights(f16x8 (&wB)[48], const float* __restrict__ W,
                                             int j, int kh, int kg) {
#pragma unroll
    for (int g = 0; g < 3; ++g)
#pragma unroll
        for (int i = 0; i < 16; ++i) {
            const float* p = W + (((size_t)g << 10) + j) * 1024 + (kh << 9) + (i << 5) + (kg << 3);
            float4 u = *(const float4*)p;
            float4 v = *(const float4*)(p + 4);
            f16x8 o;
            o[0] = (_Float16)u.x; o[1] = (_Float16)u.y; o[2] = (_Float16)u.z; o[3] = (_Float16)u.w;
            o[4] = (_Float16)v.x; o[5] = (_Float16)v.y; o[6] = (_Float16)v.z; o[7] = (_Float16)v.w;
            wB[g * 16 + i] = o;
        }
}

// One GRU phase: 512 steps. Weights in wB (registers/AGPRs), h f32 master in
// hreg. h16 ping-pong: step t reads buf[t&1], writes buf[(t+1)&1].
template <bool DEC>
__device__ __forceinline__ void phase(
    int b0, int bt, int jt, int j, int np, int kh, int kg, int r16, int tid, int lane,
    const f16x8 (&wB)[48], float (&hreg)[4],
    _Float16* __restrict__ h16A, _Float16* __restrict__ h16B,
    const float* __restrict__ Wih, const float* __restrict__ bih,
    const float* __restrict__ bhh,
    const float* __restrict__ input, const float* __restrict__ Wout, float bout_v,
    float* __restrict__ xpart, float* __restrict__ outp,
    volatile unsigned* flags, unsigned& g,
    char* Als, f32x4 (*red)[3][64], float* xv_s, float (*xnp)[16])
{
    const float wi_r = Wih[j], wi_z = Wih[1024 + j], wi_n = Wih[2048 + j];
    const float bi_r = bih[j], bi_z = bih[1024 + j], bi_n = bih[2048 + j];
    const float bh_r = bhh[j], bh_z = bhh[1024 + j], bh_n = bhh[2048 + j];
    const float wo = DEC ? Wout[j] : 0.f;

    for (int t = 0; t < T; ++t) {
        const _Float16* hp = (t & 1) ? h16B : h16A;
        _Float16* hn = (t & 1) ? h16A : h16B;

        // decoder: gather x_t = sum of 16 j-group partials (+bout); write out[:,t-1]
        if (DEC) {
            if (tid < 16) {
                float s = 0.f;
                if (t > 0) {
                    const float* xp = xpart + ((t - 1) & 1) * 4096 + (size_t)(b0 + tid) * 16;
#pragma unroll
                    for (int q = 0; q < 16; ++q) s += xp[q];
                    s += bout_v;
                    if (jt == 0) outp[(size_t)(b0 + tid) * T + (t - 1)] = s;
                }
                xv_s[tid] = s;
            }
        }

        // stage A-tile [16 x 1024] f16 into LDS, XOR-swizzled (k_byte ^= (row&7)<<4)
#pragma unroll
        for (int i = 0; i < 4; ++i) {
            int c = i * 512 + tid;
            int row = c >> 7, kc = c & 127;
            f16x8 v = *(const f16x8*)(hp + ((size_t)(b0 + row) << 10) + (kc << 3));
            *(f16x8*)(Als + row * 2048 + ((kc * 16) ^ ((row & 7) << 4))) = v;
        }
        __syncthreads();

        f32x4 aR = {0.f, 0.f, 0.f, 0.f}, aZ = {0.f, 0.f, 0.f, 0.f}, aN = {0.f, 0.f, 0.f, 0.f};
#pragma unroll
        for (int i = 0; i < 16; ++i) {
            int kb = (kh << 10) + (i << 6) + (kg << 4);
            f16x8 a = *(const f16x8*)(Als + (r16 << 11) + (kb ^ ((r16 & 7) << 4)));
            aR = __builtin_amdgcn_mfma_f32_16x16x32_f16(a, wB[i], aR, 0, 0, 0);
            aZ = __builtin_amdgcn_mfma_f32_16x16x32_f16(a, wB[16 + i], aZ, 0, 0, 0);
            aN = __builtin_amdgcn_mfma_f32_16x16x32_f16(a, wB[32 + i], aN, 0, 0, 0);
        }

        if (kh == 1) {
            red[np][0][lane] = aR; red[np][1][lane] = aZ; red[np][2][lane] = aN;
        }
        __syncthreads();

        if (kh == 0) {
            f32x4 rR = red[np][0][lane], rZ = red[np][1][lane], rN = red[np][2][lane];
            float xw[4];
#pragma unroll
            for (int reg = 0; reg < 4; ++reg) {
                int brow = kg * 4 + reg;
                int b = b0 + brow;
                float xv = DEC ? xv_s[brow] : input[(size_t)b * T + t];
                float r = sigmoidf_(xv * wi_r + bi_r + aR[reg] + rR[reg] + bh_r);
                float z = sigmoidf_(xv * wi_z + bi_z + aZ[reg] + rZ[reg] + bh_z);
                float n = tanhf_(xv * wi_n + bi_n + r * (aN[reg] + rN[reg] + bh_n));
                float hNew = (1.f - z) * n + z * hreg[reg];
                hreg[reg] = hNew;
                hn[((size_t)b << 10) + j] = (_Float16)hNew;
                xw[reg] = hNew * wo;
            }
            if (DEC) {
#pragma unroll
                for (int reg = 0; reg < 4; ++reg) {
                    float v = xw[reg];
                    v += __shfl_xor(v, 1); v += __shfl_xor(v, 2);
                    v += __shfl_xor(v, 4); v += __shfl_xor(v, 8);
                    if (r16 == 0) xnp[np][kg * 4 + reg] = v;
                }
            }
        }
        if (DEC) {
            __syncthreads();
            if (tid < 16) {
                float s = xnp[0][tid] + xnp[1][tid] + xnp[2][tid] + xnp[3][tid];
                xpart[(t & 1) * 4096 + (size_t)(b0 + tid) * 16 + jt] = s;
            }
        }
        bt_barrier(flags, bt, jt, ++g, tid);
    }
}

__global__ __launch_bounds__(512, 2) void gru_persistent(
    const float* __restrict__ input, const float* __restrict__ h_init,
    const float* __restrict__ Wih_e, const float* __restrict__ Whh_e,
    const float* __restrict__ bih_e, const float* __restrict__ bhh_e,
    const float* __restrict__ Wenc, const float* __restrict__ benc,
    const float* __restrict__ Wdec, const float* __restrict__ bdec,
    const float* __restrict__ Wih_d, const float* __restrict__ Whh_d,
    const float* __restrict__ bih_d, const float* __restrict__ bhh_d,
    const float* __restrict__ Wout, const float* __restrict__ boutp,
    float* __restrict__ featOut, float* __restrict__ outp,
    _Float16* __restrict__ h16A, _Float16* __restrict__ h16B,
    float* __restrict__ xpart, float* __restrict__ fpart,
    unsigned* flags)
{
    __shared__ __align__(16) char Als[32768];
    __shared__ f32x4 red[4][3][64];
    __shared__ float xv_s[16];
    __shared__ float xnp[4][16];
    __shared__ float fp_np[4][16][3];
    __shared__ float feats[16][3];

    const int tid = threadIdx.x;
    const int lane = tid & 63;
    const int w = tid >> 6;      // 0..7
    const int kh = w & 1;        // K-half
    const int np = w >> 1;       // 0..3 n-quadrant
    const int kg = lane >> 4;    // 0..3
    const int r16 = lane & 15;
    const int bid = blockIdx.x;
    const int bt = bid & 15, jt = bid >> 4;   // bt-group = one XCD
    const int b0 = bt * 16, j0 = jt * 64;
    const int j = j0 + np * 16 + r16;
    const float bout_v = boutp[0];
    unsigned g = 0;

    f16x8 wB[48];
    float hreg[4] = {0.f, 0.f, 0.f, 0.f};

    // ---- init: hreg + h16A from h_init ----
    if (kh == 0) {
#pragma unroll
        for (int reg = 0; reg < 4; ++reg) {
            int b = b0 + kg * 4 + reg;
            float v = h_init[((size_t)b << 10) + j];
            hreg[reg] = v;
            h16A[((size_t)b << 10) + j] = (_Float16)v;
        }
    }
    load_weights(wB, Whh_e, j, kh, kg);
    bt_barrier(flags, bt, jt, ++g, tid);

    // ---- encoder: 512 steps ----
    phase<false>(b0, bt, jt, j, np, kh, kg, r16, tid, lane, wB, hreg, h16A, h16B,
                 Wih_e, bih_e, bhh_e, input, Wout, bout_v, xpart, outp,
                 flags, g, Als, red, xv_s, xnp);

    // ---- bottleneck: fpart partials from hreg (hT) ----
    {
        float we0 = Wenc[j], we1 = Wenc[1024 + j], we2 = Wenc[2048 + j];
        if (kh == 0) {
#pragma unroll
            for (int reg = 0; reg < 4; ++reg) {
                float h = hreg[reg];
                float p0 = h * we0, p1 = h * we1, p2 = h * we2;
#pragma unroll
                for (int m = 1; m < 16; m <<= 1) {
                    p0 += __shfl_xor(p0, m);
                    p1 += __shfl_xor(p1, m);
                    p2 += __shfl_xor(p2, m);
                }
                if (r16 == 0) {
                    fp_np[np][kg * 4 + reg][0] = p0;
                    fp_np[np][kg * 4 + reg][1] = p1;
                    fp_np[np][kg * 4 + reg][2] = p2;
                }
            }
        }
        __syncthreads();
        if (tid < 48) {
            int bi = tid / 3, c = tid % 3;
            float s = fp_np[0][bi][c] + fp_np[1][bi][c] + fp_np[2][bi][c] + fp_np[3][bi][c];
            fpart[(size_t)(b0 + bi) * 48 + jt * 3 + c] = s;
        }
        bt_barrier(flags, bt, jt, ++g, tid);

        if (tid < 48) {
            int bi = tid / 3, c = tid % 3;
            float s = 0.f;
            const float* fp = fpart + (size_t)(b0 + bi) * 48 + c;
#pragma unroll
            for (int q = 0; q < 16; ++q) s += fp[q * 3];
            float f = sigmoidf_(s + benc[c]);
            feats[bi][c] = f;
            if (jt == 0) featOut[(b0 + bi) * 3 + c] = f;
        }
        __syncthreads();

        // h0 = feats @ Wdec.T + bdec  -> hreg + h16A (decoder t=0 reads h16A)
        if (kh == 0) {
#pragma unroll
            for (int reg = 0; reg < 4; ++reg) {
                int brow = kg * 4 + reg;
                int b = b0 + brow;
                float v = feats[brow][0] * Wdec[j * 3 + 0] + feats[brow][1] * Wdec[j * 3 + 1] +
                          feats[brow][2] * Wdec[j * 3 + 2] + bdec[j];
                hreg[reg] = v;
                h16A[((size_t)b << 10) + j] = (_Float16)v;
            }
        }
        load_weights(wB, Whh_d, j, kh, kg);
        bt_barrier(flags, bt, jt, ++g, tid);
    }

    // ---- decoder: 512 steps ----
    phase<true>(b0, bt, jt, j, np, kh, kg, r16, tid, lane, wB, hreg, h16A, h16B,
                Wih_d, bih_d, bhh_d, input, Wout, bout_v, xpart, outp,
                flags, g, Als, red, xv_s, xnp);

    // ---- final output column: x from step 511 (xpart slot 1) ----
    if (jt == 0 && tid < 16) {
        const float* xp = xpart + 4096 + (size_t)(b0 + tid) * 16;
        float s = 0.f;
#pragma unroll
        for (int q = 0; q < 16; ++q) s += xp[q];
        outp[(size_t)(b0 + tid) * T + (T - 1)] = s + bout_v;
    }
}

__global__ __launch_bounds__(256) void loss_partial(
    const float* __restrict__ input, const float* __restrict__ outp,
    float* __restrict__ partial)
{
    int idx = blockIdx.x * blockDim.x + threadIdx.x;
    float s = 0.f;
    for (int i = idx; i < B * T; i += gridDim.x * blockDim.x) {
        float d = input[i] - outp[i];
        s += d * d;
    }
#pragma unroll
    for (int off = 32; off; off >>= 1) s += __shfl_down(s, off);
    __shared__ float ws[4];
    if ((threadIdx.x & 63) == 0) ws[threadIdx.x >> 6] = s;
    __syncthreads();
    if (threadIdx.x == 0) partial[blockIdx.x] = ws[0] + ws[1] + ws[2] + ws[3];
}

__global__ __launch_bounds__(256) void loss_final(
    const float* __restrict__ partial, float* __restrict__ loss)
{
    int tid = threadIdx.x;
    float s = partial[tid];
#pragma unroll
    for (int off = 32; off; off >>= 1) s += __shfl_down(s, off);
    __shared__ float ws[4];
    if ((tid & 63) == 0) ws[tid >> 6] = s;
    __syncthreads();
    if (tid == 0) loss[0] = (ws[0] + ws[1] + ws[2] + ws[3]) * (1.0f / (float)(B * T));
}

extern "C" void kernel_launch(void* const* d_in, const int* in_sizes, int n_in,
                              void* d_out, int out_size, void* d_ws, size_t ws_size,
                              hipStream_t stream) {
    const float* input = (const float*)d_in[0];
    const float* h_init = (const float*)d_in[1];
    const float* Wih_e = (const float*)d_in[2];
    const float* Whh_e = (const float*)d_in[3];
    const float* bih_e = (const float*)d_in[4];
    const float* bhh_e = (const float*)d_in[5];
    const float* Wenc  = (const float*)d_in[6];
    const float* benc  = (const float*)d_in[7];
    const float* Wdec  = (const float*)d_in[8];
    const float* bdec  = (const float*)d_in[9];
    const float* Wih_d = (const float*)d_in[10];
    const float* Whh_d = (const float*)d_in[11];
    const float* bih_d = (const float*)d_in[12];
    const float* bhh_d = (const float*)d_in[13];
    const float* Wout  = (const float*)d_in[14];
    const float* bout  = (const float*)d_in[15];
    (void)in_sizes; (void)n_in; (void)out_size; (void)ws_size;

    float* out = (float*)d_out;
    float* lossp = out;                    // [1]
    float* feat = out + 1;                 // [B*CODE]
    float* outp = out + 1 + B * CODE;      // [B*T]

    // ---- workspace layout ----
    char* ws = (char*)d_ws;
    _Float16* h16A = (_Float16*)ws;                  ws += (size_t)B * H * 2;
    _Float16* h16B = (_Float16*)ws;                  ws += (size_t)B * H * 2;
    float* xpart = (float*)ws;                       ws += 2 * 4096 * 4;   // [2][256][16]
    float* fpart = (float*)ws;                       ws += (size_t)B * 48 * 4;
    float* partial = (float*)ws;                     ws += 256 * 4;
    unsigned* flags = (unsigned*)ws;                 ws += 16 * 16 * 32 * 4;  // padded flag lines

    // flags must start at 0 every call (ws poisoned once, not restored)
    hipMemsetAsync(flags, 0, 16 * 16 * 32 * 4, stream);

    gru_persistent<<<dim3(NBLK), dim3(512), 0, stream>>>(
        input, h_init, Wih_e, Whh_e, bih_e, bhh_e, Wenc, benc, Wdec, bdec,
        Wih_d, Whh_d, bih_d, bhh_d, Wout, bout,
        feat, outp, h16A, h16B, xpart, fpart, flags);

    loss_partial<<<256, 256, 0, stream>>>(input, outp, partial);
    loss_final<<<1, 256, 0, stream>>>(partial, lossp);
}

// Round 6
// 6513.448 us; speedup vs baseline: 4.1775x; 2.3485x over previous
//
#include <hip/hip_runtime.h>
#include <math.h>

#define B 256
#define T 512
#define H 1024
#define CODE 3
#define NBLK 256

typedef _Float16 f16x8 __attribute__((ext_vector_type(8)));
typedef float f32x4 __attribute__((ext_vector_type(4)));

__device__ __forceinline__ float sigmoidf_(float x) { return 1.0f / (1.0f + __expf(-x)); }
__device__ __forceinline__ float tanhf_(float x) {
    float ax = fabsf(x);
    float t = __expf(-2.0f * ax);
    float r = (1.0f - t) / (1.0f + t);
    return x < 0.f ? -r : r;
}

// ---- agent-coherent access helpers (no L2 fences needed) ----
// Stores go write-through to LLC (sc0 sc1); loads bypass L1/L2 (sc0 sc1).
// After s_waitcnt vmcnt(0), a sc0sc1 store is visible at the LLC to all XCDs.
__device__ __forceinline__ void store_f16_coh(_Float16* p, float v) {
    unsigned u = (unsigned)__builtin_bit_cast(unsigned short, (_Float16)v);
    asm volatile("global_store_short %0, %1, off sc0 sc1" :: "v"(p), "v"(u) : "memory");
}
__device__ __forceinline__ uint4 load_b16_coh(const void* p) {
    uint4 v;
    asm volatile("global_load_dwordx4 %0, %1, off sc0 sc1" : "=v"(v) : "v"(p));
    return v;
}
__device__ __forceinline__ void storef_coh(float* p, float v) {
    __hip_atomic_store(p, v, __ATOMIC_RELAXED, __HIP_MEMORY_SCOPE_AGENT);
}
__device__ __forceinline__ float loadf_coh(const float* p) {
    return __hip_atomic_load((float*)p, __ATOMIC_RELAXED, __HIP_MEMORY_SCOPE_AGENT);
}

// ---- bt-group barrier (16 blocks sharing batch rows), fence-free ----
// Every thread drains its vmem (stores reached LLC: all cross-block data is
// written sc0sc1 write-through), then one flag store + 16-lane parallel poll.
// Monotone generation -> no reset race. Group = one XCD (bid%8 const).
__device__ __forceinline__ void bt_barrier(unsigned* flags, int bt, int jt,
                                           unsigned g, int tid) {
    asm volatile("s_waitcnt vmcnt(0)" ::: "memory");
    __syncthreads();
    if (tid == 0)
        __hip_atomic_store(&flags[(bt * 16 + jt) * 32], g,
                           __ATOMIC_RELAXED, __HIP_MEMORY_SCOPE_AGENT);
    if (tid < 16) {
        while (__hip_atomic_load(&flags[(bt * 16 + tid) * 32],
                                 __ATOMIC_RELAXED, __HIP_MEMORY_SCOPE_AGENT) < g)
            __builtin_amdgcn_s_sleep(1);
    }
    __syncthreads();
}

// Load this wave's 48 B-fragments (3 gates x 16 k-chunks of its K-half) from
// f32 weights, converting to f16. j = this lane's B row; one-time cost.
__device__ __forceinline__ void load_weights(f16x8 (&wB)[48], const float* __restrict__ W,
                                             int j, int kh, int kg) {
#pragma unroll
    for (int g = 0; g < 3; ++g)
#pragma unroll
        for (int i = 0; i < 16; ++i) {
            const float* p = W + (((size_t)g << 10) + j) * 1024 + (kh << 9) + (i << 5) + (kg << 3);
            float4 u = *(const float4*)p;
            float4 v = *(const float4*)(p + 4);
            f16x8 o;
            o[0] = (_Float16)u.x; o[1] = (_Float16)u.y; o[2] = (_Float16)u.z; o[3] = (_Float16)u.w;
            o[4] = (_Float16)v.x; o[5] = (_Float16)v.y; o[6] = (_Float16)v.z; o[7] = (_Float16)v.w;
            wB[g * 16 + i] = o;
        }
}

// One GRU phase: 512 steps. Weights in wB (registers/AGPRs), h f32 master in
// hreg. h16 ping-pong: step t reads buf[t&1], writes buf[(t+1)&1].
template <bool DEC>
__device__ __forceinline__ void phase(
    int b0, int bt, int jt, int j, int np, int kh, int kg, int r16, int tid, int lane,
    const f16x8 (&wB)[48], float (&hreg)[4],
    _Float16* __restrict__ h16A, _Float16* __restrict__ h16B,
    const float* __restrict__ Wih, const float* __restrict__ bih,
    const float* __restrict__ bhh,
    const float* __restrict__ input, const float* __restrict__ Wout, float bout_v,
    float* __restrict__ xpart, float* __restrict__ outp,
    unsigned* flags, unsigned& g,
    char* Als, f32x4 (*red)[3][64], float* xv_s, float (*xnp)[16])
{
    const float wi_r = Wih[j], wi_z = Wih[1024 + j], wi_n = Wih[2048 + j];
    const float bi_r = bih[j], bi_z = bih[1024 + j], bi_n = bih[2048 + j];
    const float bh_r = bhh[j], bh_z = bhh[1024 + j], bh_n = bhh[2048 + j];
    const float wo = DEC ? Wout[j] : 0.f;
    const int kc = tid & 127;      // f16x8 chunk within row (const across i)
    const int rb = tid >> 7;       // row base 0..3

    for (int t = 0; t < T; ++t) {
        const _Float16* hp = (t & 1) ? h16B : h16A;
        _Float16* hn = (t & 1) ? h16A : h16B;

        // decoder: gather x_t = sum of 16 j-group partials (+bout); write out[:,t-1]
        if (DEC) {
            if (tid < 16) {
                float s = 0.f;
                if (t > 0) {
                    const float* xp = xpart + ((t - 1) & 1) * 4096 + (size_t)(b0 + tid) * 16;
#pragma unroll
                    for (int q = 0; q < 16; ++q) s += loadf_coh(xp + q);
                    s += bout_v;
                    if (jt == 0) outp[(size_t)(b0 + tid) * T + (t - 1)] = s;
                }
                xv_s[tid] = s;
            }
        }

        // stage A-tile [16 x 1024] f16 into LDS via coherent 16B loads,
        // XOR-swizzled (k_byte ^= (row&7)<<4)
        uint4 tmp[4];
#pragma unroll
        for (int i = 0; i < 4; ++i) {
            int row = i * 4 + rb;
            tmp[i] = load_b16_coh(hp + (((size_t)(b0 + row)) << 10) + (kc << 3));
        }
        asm volatile("s_waitcnt vmcnt(0)" ::: "memory");
#pragma unroll
        for (int i = 0; i < 4; ++i) {
            int row = i * 4 + rb;
            *(uint4*)(Als + row * 2048 + ((kc << 4) ^ ((row & 7) << 4))) = tmp[i];
        }
        __syncthreads();

        f32x4 aR = {0.f, 0.f, 0.f, 0.f}, aZ = {0.f, 0.f, 0.f, 0.f}, aN = {0.f, 0.f, 0.f, 0.f};
#pragma unroll
        for (int i = 0; i < 16; ++i) {
            int kb = (kh << 10) + (i << 6) + (kg << 4);
            f16x8 a = *(const f16x8*)(Als + (r16 << 11) + (kb ^ ((r16 & 7) << 4)));
            aR = __builtin_amdgcn_mfma_f32_16x16x32_f16(a, wB[i], aR, 0, 0, 0);
            aZ = __builtin_amdgcn_mfma_f32_16x16x32_f16(a, wB[16 + i], aZ, 0, 0, 0);
            aN = __builtin_amdgcn_mfma_f32_16x16x32_f16(a, wB[32 + i], aN, 0, 0, 0);
        }

        if (kh == 1) {
            red[np][0][lane] = aR; red[np][1][lane] = aZ; red[np][2][lane] = aN;
        }
        __syncthreads();

        if (kh == 0) {
            f32x4 rR = red[np][0][lane], rZ = red[np][1][lane], rN = red[np][2][lane];
            float xw[4];
#pragma unroll
            for (int reg = 0; reg < 4; ++reg) {
                int brow = kg * 4 + reg;
                int b = b0 + brow;
                float xv = DEC ? xv_s[brow] : input[(size_t)b * T + t];
                float r = sigmoidf_(xv * wi_r + bi_r + aR[reg] + rR[reg] + bh_r);
                float z = sigmoidf_(xv * wi_z + bi_z + aZ[reg] + rZ[reg] + bh_z);
                float n = tanhf_(xv * wi_n + bi_n + r * (aN[reg] + rN[reg] + bh_n));
                float hNew = (1.f - z) * n + z * hreg[reg];
                hreg[reg] = hNew;
                store_f16_coh(hn + ((size_t)b << 10) + j, hNew);
                xw[reg] = hNew * wo;
            }
            if (DEC) {
#pragma unroll
                for (int reg = 0; reg < 4; ++reg) {
                    float v = xw[reg];
                    v += __shfl_xor(v, 1); v += __shfl_xor(v, 2);
                    v += __shfl_xor(v, 4); v += __shfl_xor(v, 8);
                    if (r16 == 0) xnp[np][kg * 4 + reg] = v;
                }
            }
        }
        if (DEC) {
            __syncthreads();
            if (tid < 16) {
                float s = xnp[0][tid] + xnp[1][tid] + xnp[2][tid] + xnp[3][tid];
                storef_coh(xpart + (t & 1) * 4096 + (size_t)(b0 + tid) * 16 + jt, s);
            }
        }
        bt_barrier(flags, bt, jt, ++g, tid);
    }
}

__global__ __launch_bounds__(512, 2) void gru_persistent(
    const float* __restrict__ input, const float* __restrict__ h_init,
    const float* __restrict__ Wih_e, const float* __restrict__ Whh_e,
    const float* __restrict__ bih_e, const float* __restrict__ bhh_e,
    const float* __restrict__ Wenc, const float* __restrict__ benc,
    const float* __restrict__ Wdec, const float* __restrict__ bdec,
    const float* __restrict__ Wih_d, const float* __restrict__ Whh_d,
    const float* __restrict__ bih_d, const float* __restrict__ bhh_d,
    const float* __restrict__ Wout, const float* __restrict__ boutp,
    float* __restrict__ featOut, float* __restrict__ outp,
    _Float16* __restrict__ h16A, _Float16* __restrict__ h16B,
    float* __restrict__ xpart, float* __restrict__ fpart,
    unsigned* flags)
{
    __shared__ __align__(16) char Als[32768];
    __shared__ f32x4 red[4][3][64];
    __shared__ float xv_s[16];
    __shared__ float xnp[4][16];
    __shared__ float fp_np[4][16][3];
    __shared__ float feats[16][3];

    const int tid = threadIdx.x;
    const int lane = tid & 63;
    const int w = tid >> 6;      // 0..7
    const int kh = w & 1;        // K-half
    const int np = w >> 1;       // 0..3 n-quadrant
    const int kg = lane >> 4;    // 0..3
    const int r16 = lane & 15;
    const int bid = blockIdx.x;
    const int bt = bid & 15, jt = bid >> 4;   // bt-group = one XCD
    const int b0 = bt * 16, j0 = jt * 64;
    const int j = j0 + np * 16 + r16;
    const float bout_v = boutp[0];
    unsigned g = 0;

    f16x8 wB[48];
    float hreg[4] = {0.f, 0.f, 0.f, 0.f};

    // ---- init: hreg + h16A from h_init ----
    if (kh == 0) {
#pragma unroll
        for (int reg = 0; reg < 4; ++reg) {
            int b = b0 + kg * 4 + reg;
            float v = h_init[((size_t)b << 10) + j];
            hreg[reg] = v;
            store_f16_coh(h16A + ((size_t)b << 10) + j, v);
        }
    }
    load_weights(wB, Whh_e, j, kh, kg);
    bt_barrier(flags, bt, jt, ++g, tid);

    // ---- encoder: 512 steps ----
    phase<false>(b0, bt, jt, j, np, kh, kg, r16, tid, lane, wB, hreg, h16A, h16B,
                 Wih_e, bih_e, bhh_e, input, Wout, bout_v, xpart, outp,
                 flags, g, Als, red, xv_s, xnp);

    // ---- bottleneck: fpart partials from hreg (hT) ----
    {
        float we0 = Wenc[j], we1 = Wenc[1024 + j], we2 = Wenc[2048 + j];
        if (kh == 0) {
#pragma unroll
            for (int reg = 0; reg < 4; ++reg) {
                float h = hreg[reg];
                float p0 = h * we0, p1 = h * we1, p2 = h * we2;
#pragma unroll
                for (int m = 1; m < 16; m <<= 1) {
                    p0 += __shfl_xor(p0, m);
                    p1 += __shfl_xor(p1, m);
                    p2 += __shfl_xor(p2, m);
                }
                if (r16 == 0) {
                    fp_np[np][kg * 4 + reg][0] = p0;
                    fp_np[np][kg * 4 + reg][1] = p1;
                    fp_np[np][kg * 4 + reg][2] = p2;
                }
            }
        }
        __syncthreads();
        if (tid < 48) {
            int bi = tid / 3, c = tid % 3;
            float s = fp_np[0][bi][c] + fp_np[1][bi][c] + fp_np[2][bi][c] + fp_np[3][bi][c];
            storef_coh(fpart + (size_t)(b0 + bi) * 48 + jt * 3 + c, s);
        }
        bt_barrier(flags, bt, jt, ++g, tid);

        if (tid < 48) {
            int bi = tid / 3, c = tid % 3;
            float s = 0.f;
            const float* fp = fpart + (size_t)(b0 + bi) * 48 + c;
#pragma unroll
            for (int q = 0; q < 16; ++q) s += loadf_coh(fp + q * 3);
            float f = sigmoidf_(s + benc[c]);
            feats[bi][c] = f;
            if (jt == 0) featOut[(b0 + bi) * 3 + c] = f;
        }
        __syncthreads();

        // h0 = feats @ Wdec.T + bdec  -> hreg + h16A (decoder t=0 reads h16A)
        if (kh == 0) {
#pragma unroll
            for (int reg = 0; reg < 4; ++reg) {
                int brow = kg * 4 + reg;
                int b = b0 + brow;
                float v = feats[brow][0] * Wdec[j * 3 + 0] + feats[brow][1] * Wdec[j * 3 + 1] +
                          feats[brow][2] * Wdec[j * 3 + 2] + bdec[j];
                hreg[reg] = v;
                store_f16_coh(h16A + ((size_t)b << 10) + j, v);
            }
        }
        load_weights(wB, Whh_d, j, kh, kg);
        bt_barrier(flags, bt, jt, ++g, tid);
    }

    // ---- decoder: 512 steps ----
    phase<true>(b0, bt, jt, j, np, kh, kg, r16, tid, lane, wB, hreg, h16A, h16B,
                Wih_d, bih_d, bhh_d, input, Wout, bout_v, xpart, outp,
                flags, g, Als, red, xv_s, xnp);

    // ---- final output column: x from step 511 (xpart slot 1) ----
    if (jt == 0 && tid < 16) {
        const float* xp = xpart + 4096 + (size_t)(b0 + tid) * 16;
        float s = 0.f;
#pragma unroll
        for (int q = 0; q < 16; ++q) s += loadf_coh(xp + q);
        outp[(size_t)(b0 + tid) * T + (T - 1)] = s + bout_v;
    }
}

__global__ __launch_bounds__(256) void loss_partial(
    const float* __restrict__ input, const float* __restrict__ outp,
    float* __restrict__ partial)
{
    int idx = blockIdx.x * blockDim.x + threadIdx.x;
    float s = 0.f;
    for (int i = idx; i < B * T; i += gridDim.x * blockDim.x) {
        float d = input[i] - outp[i];
        s += d * d;
    }
#pragma unroll
    for (int off = 32; off; off >>= 1) s += __shfl_down(s, off);
    __shared__ float ws[4];
    if ((threadIdx.x & 63) == 0) ws[threadIdx.x >> 6] = s;
    __syncthreads();
    if (threadIdx.x == 0) partial[blockIdx.x] = ws[0] + ws[1] + ws[2] + ws[3];
}

__global__ __launch_bounds__(256) void loss_final(
    const float* __restrict__ partial, float* __restrict__ loss)
{
    int tid = threadIdx.x;
    float s = partial[tid];
#pragma unroll
    for (int off = 32; off; off >>= 1) s += __shfl_down(s, off);
    __shared__ float ws[4];
    if ((tid & 63) == 0) ws[tid >> 6] = s;
    __syncthreads();
    if (tid == 0) loss[0] = (ws[0] + ws[1] + ws[2] + ws[3]) * (1.0f / (float)(B * T));
}

extern "C" void kernel_launch(void* const* d_in, const int* in_sizes, int n_in,
                              void* d_out, int out_size, void* d_ws, size_t ws_size,
                              hipStream_t stream) {
    const float* input = (const float*)d_in[0];
    const float* h_init = (const float*)d_in[1];
    const float* Wih_e = (const float*)d_in[2];
    const float* Whh_e = (const float*)d_in[3];
    const float* bih_e = (const float*)d_in[4];
    const float* bhh_e = (const float*)d_in[5];
    const float* Wenc  = (const float*)d_in[6];
    const float* benc  = (const float*)d_in[7];
    const float* Wdec  = (const float*)d_in[8];
    const float* bdec  = (const float*)d_in[9];
    const float* Wih_d = (const float*)d_in[10];
    const float* Whh_d = (const float*)d_in[11];
    const float* bih_d = (const float*)d_in[12];
    const float* bhh_d = (const float*)d_in[13];
    const float* Wout  = (const float*)d_in[14];
    const float* bout  = (const float*)d_in[15];
    (void)in_sizes; (void)n_in; (void)out_size; (void)ws_size;

    float* out = (float*)d_out;
    float* lossp = out;                    // [1]
    float* feat = out + 1;                 // [B*CODE]
    float* outp = out + 1 + B * CODE;      // [B*T]

    // ---- workspace layout ----
    char* ws = (char*)d_ws;
    _Float16* h16A = (_Float16*)ws;                  ws += (size_t)B * H * 2;
    _Float16* h16B = (_Float16*)ws;                  ws += (size_t)B * H * 2;
    float* xpart = (float*)ws;                       ws += 2 * 4096 * 4;   // [2][256][16]
    float* fpart = (float*)ws;                       ws += (size_t)B * 48 * 4;
    float* partial = (float*)ws;                     ws += 256 * 4;
    unsigned* flags = (unsigned*)ws;                 ws += 16 * 16 * 32 * 4;  // padded flag lines

    // flags must start at 0 every call (ws poisoned once, not restored)
    hipMemsetAsync(flags, 0, 16 * 16 * 32 * 4, stream);

    gru_persistent<<<dim3(NBLK), dim3(512), 0, stream>>>(
        input, h_init, Wih_e, Whh_e, bih_e, bhh_e, Wenc, benc, Wdec, bdec,
        Wih_d, Whh_d, bih_d, bhh_d, Wout, bout,
        feat, outp, h16A, h16B, xpart, fpart, flags);

    loss_partial<<<256, 256, 0, stream>>>(input, outp, partial);
    loss_final<<<1, 256, 0, stream>>>(partial, lossp);
}